// Round 2
// baseline (554.171 us; speedup 1.0000x reference)
//
#include <hip/hip_runtime.h>
#include <hip/hip_bf16.h>

typedef unsigned int u32;
typedef unsigned short u16;

#define NLOC 8192      // B*HWC
#define CDIM 512
#define LCTX 32
#define NH   8
#define DH   64

__device__ __forceinline__ float bl(u32 u){ return __uint_as_float(u << 16); }
__device__ __forceinline__ float bh(u32 u){ return __uint_as_float(u & 0xffff0000u); }
__device__ __forceinline__ float b2f(u16 u){ return __uint_as_float(((u32)u) << 16); }
__device__ __forceinline__ u16 f2b(float f){
  u32 u = __float_as_uint(f);
  return (u16)((u + 0x7fffu + ((u >> 16) & 1u)) >> 16);
}
__device__ __forceinline__ u32 pk2(float a, float b){
  return (u32)f2b(a) | ((u32)f2b(b) << 16);
}

// K0: weights -> bf16. kwb[o][c] = k_w[o][c]; vwt[c][o] = v_w[o][c] (transposed).
__global__ __launch_bounds__(256) void k0_prep(const float* __restrict__ kw,
                                               const float* __restrict__ vw,
                                               u16* __restrict__ kwb,
                                               u16* __restrict__ vwt){
  int i = blockIdx.x * 256 + threadIdx.x;      // 262144 total
  int o = i >> 9, c = i & 511;
  kwb[i] = f2b(kw[i]);
  vwt[c * 512 + o] = f2b(vw[i]);
}

// K1: LayerNorm + kq[t,h,c] = sum_d qln[t,h*64+d] * k_w[h*64+d,c].  32 locations/block.
// (unchanged from round 1 — known good)
__global__ __launch_bounds__(256) void k1_lnkq(const float* __restrict__ q,
                                               const float* __restrict__ lng,
                                               const float* __restrict__ lnb,
                                               const u16* __restrict__ kwb,
                                               u16* __restrict__ kqw,   // [local_bn][8][512] bf16
                                               int base){
  __shared__ u16 qT[512 * 32];                 // [o][t]
  int tid = threadIdx.x;
  {
    int t = tid >> 3, sub = tid & 7;
    long bn = (long)base + blockIdx.x * 32 + t;
    const float* qr = q + bn * 512;
    float xv[64];
    float s = 0.f, s2 = 0.f;
#pragma unroll
    for (int k = 0; k < 64; k++){ float v = qr[sub + 8 * k]; xv[k] = v; s += v; s2 += v * v; }
    s  += __shfl_xor(s, 1);  s2 += __shfl_xor(s2, 1);
    s  += __shfl_xor(s, 2);  s2 += __shfl_xor(s2, 2);
    s  += __shfl_xor(s, 4);  s2 += __shfl_xor(s2, 4);
    float mu = s * (1.f / 512.f);
    float rstd = rsqrtf(s2 * (1.f / 512.f) - mu * mu + 1e-5f);
#pragma unroll
    for (int k = 0; k < 64; k++){
      int c = sub + 8 * k;
      float v = (xv[k] - mu) * rstd * lng[c] + lnb[c];
      qT[c * 32 + t] = f2b(v);
    }
  }
  __syncthreads();
  int h = tid >> 5, tg = (tid >> 3) & 3, cg = tid & 7;
  for (int co = 0; co < 8; co++){
    float acc[8][8];
#pragma unroll
    for (int i = 0; i < 8; i++)
#pragma unroll
      for (int j = 0; j < 8; j++) acc[i][j] = 0.f;
    for (int d = 0; d < 64; d++){
      int o = h * 64 + d;
      uint4 qv = *(const uint4*)&qT[o * 32 + tg * 8];
      uint4 wv = *(const uint4*)&kwb[o * 512 + co * 64 + cg * 8];
      float qf[8] = { bl(qv.x), bh(qv.x), bl(qv.y), bh(qv.y), bl(qv.z), bh(qv.z), bl(qv.w), bh(qv.w) };
      float wf[8] = { bl(wv.x), bh(wv.x), bl(wv.y), bh(wv.y), bl(wv.z), bh(wv.z), bl(wv.w), bh(wv.w) };
#pragma unroll
      for (int i = 0; i < 8; i++)
#pragma unroll
        for (int j = 0; j < 8; j++) acc[i][j] += qf[i] * wf[j];
    }
#pragma unroll
    for (int i = 0; i < 8; i++){
      long lbn = (long)blockIdx.x * 32 + tg * 8 + i;
      uint4 st;
      st.x = pk2(acc[i][0], acc[i][1]); st.y = pk2(acc[i][2], acc[i][3]);
      st.z = pk2(acc[i][4], acc[i][5]); st.w = pk2(acc[i][6], acc[i][7]);
      *(uint4*)&kqw[(lbn * 8 + h) * 512 + co * 64 + cg * 8] = st;
    }
  }
}

// K23: fused attention core + output projection.
// Block = 8 locations, 512 threads. Dynamic LDS layout (u16 units):
//   ctxs : 2 x [32][520]        (double-buffered ctx, bf16)     0     .. 33280
//   kqsb : 2 x [8][520]         (double-buffered kq, bf16)      33280 .. 41600
//   wctx : [8t][8h][514]        (weighted ctx, bf16)            41600 .. 74496
//   smat : [8][33] f32          (scores for softmax)            byte 148992
//   wls  : [8][33] f32          (softmax weights)               byte 150048
// total 151104 B
#define K23_LDS 151104
__global__ __launch_bounds__(512) void k23_attn_out(const float* __restrict__ ctx,
                                                    const u16* __restrict__ kqw,
                                                    const u16* __restrict__ vwt,
                                                    const float* __restrict__ vb,
                                                    float* __restrict__ out,
                                                    int base){
  extern __shared__ u16 lds[];
  u16* ctxs  = lds;                 // [buf*16640 + l*520 + c]
  u16* kqsb  = lds + 33280;         // [buf*4160 + h*520 + c]
  u16* wctxs = lds + 41600;         // [(t*8+h)*514 + c]
  float* smat = (float*)(lds + 74496);        // [h*33 + l]
  float* wls  = smat + 264;                   // [h*33 + l]

  int tid = threadIdx.x;
  long l0  = (long)blockIdx.x * 8;            // local loc base (for kq/ws indexing)
  long bn0 = (long)base + l0;                 // global loc base

  // ---- prologue: stage loc 0 into buffer 0 ----
  {
    const float4* cp = (const float4*)(ctx + bn0 * (32 * 512));
    float4 rv[8];
#pragma unroll
    for (int i = 0; i < 8; i++) rv[i] = cp[i * 512 + tid];
    uint4 kqv = ((const uint4*)(kqw + l0 * 4096))[tid];
#pragma unroll
    for (int i = 0; i < 8; i++){
      int e0 = (i * 512 + tid) * 4;
      int l = e0 >> 9, col = e0 & 511;
      uint2 pk; pk.x = pk2(rv[i].x, rv[i].y); pk.y = pk2(rv[i].z, rv[i].w);
      *(uint2*)&ctxs[l * 520 + col] = pk;
    }
    { int hh = tid >> 6, cc = (tid & 63) * 8;
      *(uint4*)&kqsb[hh * 520 + cc] = kqv; }
  }
  __syncthreads();

  // ---- main loop over 8 locations ----
  for (int t = 0; t < 8; t++){
    int cur = t & 1, nxt = cur ^ 1;
    // issue next-loc global loads early (T14: issue-early / write-late)
    float4 rv[8];
    uint4 kqv;
    if (t < 7){
      const float4* cp = (const float4*)(ctx + (bn0 + t + 1) * (32 * 512));
#pragma unroll
      for (int i = 0; i < 8; i++) rv[i] = cp[i * 512 + tid];
      kqv = ((const uint4*)(kqw + (l0 + t + 1) * 4096))[tid];
    }

    // --- scores: thread = (l = tid>>4, h = (tid>>1)&7, e = tid&1), 256 c each ---
    {
      int l = tid >> 4, h = (tid >> 1) & 7, e = tid & 1;
      const u16* crow = &ctxs[cur * 16640 + l * 520 + e * 256];
      const u16* krow = &kqsb[cur * 4160 + h * 520 + e * 256];
      float s0 = 0.f, s1 = 0.f, s2 = 0.f, s3 = 0.f;
#pragma unroll 8
      for (int cq = 0; cq < 64; cq++){
        uint2 cv = *(const uint2*)&crow[cq * 4];
        uint2 kv = *(const uint2*)&krow[cq * 4];
        s0 += bl(cv.x) * bl(kv.x); s1 += bh(cv.x) * bh(kv.x);
        s2 += bl(cv.y) * bl(kv.y); s3 += bh(cv.y) * bh(kv.y);
      }
      float s = (s0 + s1) + (s2 + s3);
      s += __shfl_xor(s, 1);                 // combine the two c-halves
      if (!(tid & 1)) smat[h * 33 + l] = s;
    }
    __syncthreads();

    // --- softmax over l per h (first 256 threads, thread = (l = tid>>3, h = tid&7)) ---
    if (tid < 256){
      int l = tid >> 3, h = tid & 7;
      const float* sr = &smat[h * 33];
      float mx = sr[0];
#pragma unroll
      for (int j = 1; j < 32; j++) mx = fmaxf(mx, sr[j]);
      float S = 0.f;
#pragma unroll
      for (int j = 0; j < 32; j++) S += __expf(sr[j] - mx);
      wls[h * 33 + l] = __expf(sr[l] - mx) / S;
    }
    __syncthreads();

    // --- pv: wctx[t][h][c] = sum_l w[h,l]*ctx[l,c]; thread = (cp2 = tid&255, h0 = tid>>8) ---
    {
      int cp2 = tid & 255, h0 = tid >> 8;
      const u16* cb = &ctxs[cur * 16640 + 2 * cp2];
      float a0=0.f,b0=0.f,a1=0.f,b1=0.f,a2=0.f,b2=0.f,a3=0.f,b3=0.f;
#pragma unroll 4
      for (int l = 0; l < 32; l++){
        u32 cv = *(const u32*)&cb[l * 520];
        float x = bl(cv), y = bh(cv);
        float w0 = wls[(h0    ) * 33 + l];
        float w1 = wls[(h0 + 2) * 33 + l];
        float w2 = wls[(h0 + 4) * 33 + l];
        float w3 = wls[(h0 + 6) * 33 + l];
        a0 += w0 * x; b0 += w0 * y;
        a1 += w1 * x; b1 += w1 * y;
        a2 += w2 * x; b2 += w2 * y;
        a3 += w3 * x; b3 += w3 * y;
      }
      int c = 2 * cp2;
      *(u32*)&wctxs[(t * 8 + h0    ) * 514 + c] = pk2(a0, b0);
      *(u32*)&wctxs[(t * 8 + h0 + 2) * 514 + c] = pk2(a1, b1);
      *(u32*)&wctxs[(t * 8 + h0 + 4) * 514 + c] = pk2(a2, b2);
      *(u32*)&wctxs[(t * 8 + h0 + 6) * 514 + c] = pk2(a3, b3);
    }

    // --- write-late: staged next-loc data into LDS ---
    if (t < 7){
#pragma unroll
      for (int i = 0; i < 8; i++){
        int e0 = (i * 512 + tid) * 4;
        int l = e0 >> 9, col = e0 & 511;
        uint2 pk; pk.x = pk2(rv[i].x, rv[i].y); pk.y = pk2(rv[i].z, rv[i].w);
        *(uint2*)&ctxs[nxt * 16640 + l * 520 + col] = pk;
      }
      int hh = tid >> 6, cc = (tid & 63) * 8;
      *(uint4*)&kqsb[nxt * 4160 + hh * 520 + cc] = kqv;
    }
    __syncthreads();
  }

  // ---- output projection: out[t,h,d] = sum_c wctx[t,h,c]*vwt[c,h*64+d] + vb ----
  {
    int h = tid >> 6, dg = (tid >> 3) & 7, t = tid & 7;
    const u16* wrow = &wctxs[(t * 8 + h) * 514];
    const u16* vcol = &vwt[h * 64 + dg * 8];
    float acc[8];
#pragma unroll
    for (int j = 0; j < 8; j++) acc[j] = 0.f;
#pragma unroll 4
    for (int c = 0; c < 512; c++){
      float w = b2f(wrow[c]);
      uint4 vv = *(const uint4*)&vcol[c * 512];
      acc[0] += w * bl(vv.x); acc[1] += w * bh(vv.x);
      acc[2] += w * bl(vv.y); acc[3] += w * bh(vv.y);
      acc[4] += w * bl(vv.z); acc[5] += w * bh(vv.z);
      acc[6] += w * bl(vv.w); acc[7] += w * bh(vv.w);
    }
    long bn = bn0 + t;
    long b = bn >> 12, n = bn & 4095;
    float* op = out + (((b * 8 + h) * 4096 + n) << 6) + dg * 8;
    float4 o0, o1;
    o0.x = acc[0] + vb[h * 64 + dg * 8 + 0];
    o0.y = acc[1] + vb[h * 64 + dg * 8 + 1];
    o0.z = acc[2] + vb[h * 64 + dg * 8 + 2];
    o0.w = acc[3] + vb[h * 64 + dg * 8 + 3];
    o1.x = acc[4] + vb[h * 64 + dg * 8 + 4];
    o1.y = acc[5] + vb[h * 64 + dg * 8 + 5];
    o1.z = acc[6] + vb[h * 64 + dg * 8 + 6];
    o1.w = acc[7] + vb[h * 64 + dg * 8 + 7];
    *(float4*)op = o0;
    *((float4*)op + 1) = o1;
  }
}

extern "C" void kernel_launch(void* const* d_in, const int* in_sizes, int n_in,
                              void* d_out, int out_size, void* d_ws, size_t ws_size,
                              hipStream_t stream){
  const float* q   = (const float*)d_in[0];
  const float* ctx = (const float*)d_in[1];
  const float* kw  = (const float*)d_in[2];
  // d_in[3] = k_b : cancels in softmax, unused
  const float* vw  = (const float*)d_in[4];
  const float* vb  = (const float*)d_in[5];
  const float* lng = (const float*)d_in[6];
  const float* lnb = (const float*)d_in[7];
  float* out = (float*)d_out;

  u16* kwb = (u16*)d_ws;                 // 512 KB
  u16* vwt = kwb + 512 * 512;            // 512 KB
  u16* kqw = vwt + 512 * 512;            // CH * 8 KB

  size_t avail = ws_size > (size_t)(1 << 20) ? ws_size - (size_t)(1 << 20) : 0;
  long CH = (long)(avail / 8192);        // 8 KB per location
  if (CH > NLOC) CH = NLOC;
  CH &= ~31L;
  if (CH < 32) CH = 32;

  hipFuncSetAttribute((const void*)k23_attn_out,
                      hipFuncAttributeMaxDynamicSharedMemorySize, K23_LDS);

  hipLaunchKernelGGL(k0_prep, dim3(1024), dim3(256), 0, stream, kw, vw, kwb, vwt);
  for (long base = 0; base < NLOC; base += CH){
    long M = NLOC - base; if (M > CH) M = CH;
    hipLaunchKernelGGL(k1_lnkq, dim3(M / 32), dim3(256), 0, stream, q, lng, lnb, kwb, kqw, (int)base);
    hipLaunchKernelGGL(k23_attn_out, dim3(M / 8), dim3(512), K23_LDS, stream,
                       ctx, kqw, vwt, vb, out, (int)base);
  }
}

// Round 4
// 291.442 us; speedup vs baseline: 1.9015x; 1.9015x over previous
//
#include <hip/hip_runtime.h>
#include <hip/hip_bf16.h>

typedef unsigned int u32;
typedef unsigned short u16;
typedef __attribute__((ext_vector_type(8))) short short8;
typedef __attribute__((ext_vector_type(4))) float f32x4;

#define NLOC 8192      // B*HWC
#define LCTX 32
#define NH   8

__device__ __forceinline__ float bl(u32 u){ return __uint_as_float(u << 16); }
__device__ __forceinline__ float bh(u32 u){ return __uint_as_float(u & 0xffff0000u); }
__device__ __forceinline__ u16 f2b(float f){
  u32 u = __float_as_uint(f);
  return (u16)((u + 0x7fffu + ((u >> 16) & 1u)) >> 16);
}
__device__ __forceinline__ u32 pk2(float a, float b){
  return (u32)f2b(a) | ((u32)f2b(b) << 16);
}
#define MFMA16(a, b, c) __builtin_amdgcn_mfma_f32_16x16x32_bf16(a, b, c, 0, 0, 0)

// K0: kwt[c][o] = bf16(k_w[o][c]) (transposed, Bt for k1m);
//     vwb[o][c] = bf16(v_w[o][c]) (plain, Bt for k3m).
__global__ __launch_bounds__(256) void k0_prep(const float* __restrict__ kw,
                                               const float* __restrict__ vw,
                                               u16* __restrict__ kwt,
                                               u16* __restrict__ vwb){
  int i = blockIdx.x * 256 + threadIdx.x;      // 262144
  int o = i >> 9, c = i & 511;
  kwt[c * 512 + o] = f2b(kw[i]);
  vwb[i] = f2b(vw[i]);
}

// K1m: LayerNorm + kq via MFMA. Block = 32 locs, 256 thr.
// kq[t,h,c] = sum_d qln[t,h*64+d] * kw[h*64+d,c]; A = qln [32t][512o] (LDS,
// swizzled), Bt = kwt [c][o] (global/L2). Out kqw bf16 [loc][8][512].
#define K1_LDS (32768 + 32 * 520 * 2)
__global__ __launch_bounds__(256) void k1m(const float* __restrict__ q,
                                           const float* __restrict__ lng,
                                           const float* __restrict__ lnb,
                                           const u16* __restrict__ kwt,
                                           u16* __restrict__ kqw,
                                           int base){
  extern __shared__ char smem[];
  char* qs = smem;                         // swizzled bf16 [32 rows][1024 B]
  u16* ktmp = (u16*)(smem + 32768);        // [32][520]
  int tid = threadIdx.x;
  int lane = tid & 63, w = tid >> 6;
  // ---- LayerNorm -> qs (bf16, swizzled) ----
  {
    int t = tid >> 3, sub = tid & 7;
    long bn = (long)base + (long)blockIdx.x * 32 + t;
    const float4* qr = (const float4*)(q + bn * 512);
    float4 xv[16];
    float s = 0.f, s2 = 0.f;
#pragma unroll
    for (int j = 0; j < 16; j++){
      float4 v = qr[sub + 8 * j];
      xv[j] = v;
      s += v.x + v.y + v.z + v.w;
      s2 += v.x*v.x + v.y*v.y + v.z*v.z + v.w*v.w;
    }
    s  += __shfl_xor(s, 1);  s2 += __shfl_xor(s2, 1);
    s  += __shfl_xor(s, 2);  s2 += __shfl_xor(s2, 2);
    s  += __shfl_xor(s, 4);  s2 += __shfl_xor(s2, 4);
    float mu = s * (1.f / 512.f);
    float rstd = rsqrtf(s2 * (1.f / 512.f) - mu * mu + 1e-5f);
    int sw = (t & 7) << 4;
#pragma unroll
    for (int j = 0; j < 16; j++){
      float e[4] = { xv[j].x, xv[j].y, xv[j].z, xv[j].w };
#pragma unroll
      for (int i = 0; i < 4; i++){
        int c = (sub + 8 * j) * 4 + i;
        float v = (e[i] - mu) * rstd * lng[c] + lnb[c];
        *(u16*)(qs + t * 1024 + ((2 * c) ^ sw)) = f2b(v);
      }
    }
  }
  __syncthreads();
  // ---- per-head MFMA: 2 Mtiles x 8 Ntiles(128 cols per wave) x 2 Ksteps ----
  int l_lo = lane & 15, kg = lane >> 4;
  for (int h = 0; h < 8; h++){
    short8 afr[2][2];
#pragma unroll
    for (int mt = 0; mt < 2; mt++)
#pragma unroll
      for (int ks = 0; ks < 2; ks++){
        int trow = l_lo + 16 * mt;
        afr[mt][ks] = *(const short8*)(qs + trow * 1024 +
                      ((h * 128 + ks * 64 + kg * 16) ^ ((trow & 7) << 4)));
      }
#pragma unroll
    for (int nt = 0; nt < 8; nt++){
      int cb = w * 128 + nt * 16 + l_lo;
      f32x4 acc0 = {0.f,0.f,0.f,0.f}, acc1 = {0.f,0.f,0.f,0.f};
#pragma unroll
      for (int ks = 0; ks < 2; ks++){
        short8 bfr = *(const short8*)&kwt[cb * 512 + h * 64 + ks * 32 + kg * 8];
        acc0 = MFMA16(afr[0][ks], bfr, acc0);
        acc1 = MFMA16(afr[1][ks], bfr, acc1);
      }
      int ccol = w * 128 + nt * 16 + l_lo;
#pragma unroll
      for (int r = 0; r < 4; r++){
        ktmp[(kg * 4 + r) * 520 + ccol]      = f2b(acc0[r]);
        ktmp[(16 + kg * 4 + r) * 520 + ccol] = f2b(acc1[r]);
      }
    }
    __syncthreads();
    // cooperative coalesced write of this head's kq
    {
      int tr = tid >> 3, cblk = (tid & 7) * 64;
      long lbn = (long)blockIdx.x * 32 + tr;
#pragma unroll
      for (int j = 0; j < 8; j++)
        *(uint4*)&kqw[(lbn * 8 + h) * 512 + cblk + j * 8] =
            *(const uint4*)&ktmp[tr * 520 + cblk + j * 8];
    }
    __syncthreads();
  }
}

// K2m: per-location attention core. MFMA scores + VALU softmax/pv.
// Block = 1 loc, 256 thr. Reads kq, writes wctx IN PLACE over kq region.
__global__ __launch_bounds__(256) void k2m(const float* __restrict__ ctx,
                                           u16* __restrict__ kqw,  // in: kq, out: wctx
                                           int base){
  __shared__ char ctxs[32 * 1024];          // bf16 [32 l][1024 B], XOR-swizzled
  __shared__ char kqs[8 * 1024];            // bf16 [8 h][1024 B], XOR-swizzled
  __shared__ float smat4[4 * 32 * 8];       // per-wave score partials [w][l][h]
  __shared__ float ssum[32 * 8];            // summed scores [l][h]
  __shared__ __align__(16) float wls[32 * 8]; // softmax weights [l][h]
  int tid = threadIdx.x;
  int lane = tid & 63, w = tid >> 6;
  long bn = (long)base + blockIdx.x;
  // ---- stage ctx -> bf16 swizzled LDS ----
  const float4* cp = (const float4*)(ctx + bn * (32 * 512));
#pragma unroll
  for (int i = 0; i < 16; i++){
    float4 v = cp[i * 256 + tid];
    int e0 = (i * 256 + tid) * 4;
    int l = e0 >> 9, col = e0 & 511;
    uint2 pk; pk.x = pk2(v.x, v.y); pk.y = pk2(v.z, v.w);
    *(uint2*)(ctxs + l * 1024 + ((col * 2) ^ ((l & 7) << 4))) = pk;
  }
  // ---- stage kq (bf16) -> swizzled LDS ----
  const u32* kqp = (const u32*)(kqw + (long)blockIdx.x * 4096);
#pragma unroll
  for (int r = 0; r < 8; r++){
    int m = r * 256 + tid;
    u32 u = kqp[m];
    int e0 = m * 2;
    int h = e0 >> 9, c = e0 & 511;
    *(u32*)(kqs + h * 1024 + ((c * 2) ^ (h << 4))) = u;
  }
  __syncthreads();
  // ---- scores via MFMA: [32l x 512c] x [512c x 8h]; K split across waves ----
  {
    int l_lo = lane & 15, kg = lane >> 4, hb = lane & 7;
    f32x4 acc0 = {0.f,0.f,0.f,0.f}, acc1 = {0.f,0.f,0.f,0.f};
#pragma unroll
    for (int s = 0; s < 4; s++){
      int coff = (w * 4 + s) * 64 + kg * 16;
      short8 bfr = *(const short8*)(kqs + hb * 1024 + (coff ^ (hb << 4)));
      short8 a0 = *(const short8*)(ctxs + l_lo * 1024 + (coff ^ ((l_lo & 7) << 4)));
      int l1 = l_lo + 16;
      short8 a1 = *(const short8*)(ctxs + l1 * 1024 + (coff ^ ((l1 & 7) << 4)));
      acc0 = MFMA16(a0, bfr, acc0);
      acc1 = MFMA16(a1, bfr, acc1);
    }
    if (l_lo < 8){
#pragma unroll
      for (int r = 0; r < 4; r++){
        smat4[(w * 32 + kg * 4 + r) * 8 + l_lo]      = acc0[r];
        smat4[(w * 32 + 16 + kg * 4 + r) * 8 + l_lo] = acc1[r];
      }
    }
  }
  __syncthreads();
  // ---- reduce partials + softmax over l per h ----
  {
    int l = tid >> 3, h = tid & 7;
    int ix = l * 8 + h;
    float sv = smat4[ix] + smat4[256 + ix] + smat4[512 + ix] + smat4[768 + ix];
    ssum[ix] = sv;
  }
  __syncthreads();
  {
    int l = tid >> 3, h = tid & 7;
    float sv = ssum[l * 8 + h];
    float mx = ssum[h];
#pragma unroll
    for (int j = 1; j < 32; j++) mx = fmaxf(mx, ssum[j * 8 + h]);
    float S = 0.f;
#pragma unroll
    for (int j = 0; j < 32; j++) S += __expf(ssum[j * 8 + h] - mx);
    wls[l * 8 + h] = __expf(sv - mx) / S;
  }
  __syncthreads();
  // ---- pv (VALU): wctx[h,c] = sum_l w[h,l]*ctx[l,c]; thread owns c={2tid,2tid+1} ----
  float acc[16];
#pragma unroll
  for (int i = 0; i < 16; i++) acc[i] = 0.f;
#pragma unroll 4
  for (int l2 = 0; l2 < 32; l2++){
    u32 cv = *(const u32*)(ctxs + l2 * 1024 + ((4 * tid) ^ ((l2 & 7) << 4)));
    float x = bl(cv), y = bh(cv);
    float4 w0 = *(const float4*)&wls[l2 * 8];
    float4 w1 = *(const float4*)&wls[l2 * 8 + 4];
    acc[0] += w0.x * x; acc[1] += w0.x * y;
    acc[2] += w0.y * x; acc[3] += w0.y * y;
    acc[4] += w0.z * x; acc[5] += w0.z * y;
    acc[6] += w0.w * x; acc[7] += w0.w * y;
    acc[8] += w1.x * x; acc[9] += w1.x * y;
    acc[10]+= w1.y * x; acc[11]+= w1.y * y;
    acc[12]+= w1.z * x; acc[13]+= w1.z * y;
    acc[14]+= w1.w * x; acc[15]+= w1.w * y;
  }
  u32* wp = (u32*)(kqw + (long)blockIdx.x * 4096);
#pragma unroll
  for (int hh = 0; hh < 8; hh++)
    wp[hh * 256 + tid] = pk2(acc[hh * 2], acc[hh * 2 + 1]);
}

// K3m: out[t,h,d] = sum_c wctx[t,h,c] * v_w[h*64+d,c] + v_b, via MFMA.
// Block = 32 locs, 256 thr. A = wctx head-slice [32t][512c] staged in LDS
// (double-buffered over h, runtime byte-offset indexing — no LDS pointer
// arrays: hipcc rejects addrspacecast static initializers); Bt = vwb from L2.
#define K3_TILE (32 * 520 * 2)
#define K3_LDS (2 * K3_TILE)
__global__ __launch_bounds__(256) void k3m(const u16* __restrict__ wctx,
                                           const u16* __restrict__ vwb,
                                           const float* __restrict__ vb,
                                           float* __restrict__ out,
                                           int base){
  extern __shared__ char smem[];
  int tid = threadIdx.x;
  int lane = tid & 63, w = tid >> 6;
  int tr = tid >> 3, cblk = (tid & 7) * 64;
  long lbn = (long)blockIdx.x * 32;
  // prologue: stage h=0 into buffer 0
#pragma unroll
  for (int j = 0; j < 8; j++)
    *(uint4*)(smem + (tr * 520 + cblk + j * 8) * 2) =
        *(const uint4*)&wctx[((lbn + tr) * 8 + 0) * 512 + cblk + j * 8];
  int l_lo = lane & 15, kg = lane >> 4;
  int mt = w & 1, ntb = (w >> 1) * 2;
  for (int h = 0; h < 8; h++){
    int cur = h & 1, nxt = cur ^ 1;
    __syncthreads();                       // buffer cur ready
    uint4 pre[8];
    if (h < 7){
#pragma unroll
      for (int j = 0; j < 8; j++)
        pre[j] = *(const uint4*)&wctx[((lbn + tr) * 8 + (h + 1)) * 512 + cblk + j * 8];
    }
    // compute this head
    f32x4 acc0 = {0.f,0.f,0.f,0.f}, acc1 = {0.f,0.f,0.f,0.f};
    int trow = mt * 16 + l_lo;
    const char* arow = smem + cur * K3_TILE + trow * 520 * 2;
#pragma unroll
    for (int ks = 0; ks < 16; ks++){
      short8 a = *(const short8*)(arow + ks * 64 + kg * 16);
      int o0 = h * 64 + ntb * 16 + l_lo;
      short8 b0 = *(const short8*)&vwb[o0 * 512 + ks * 32 + kg * 8];
      short8 b1 = *(const short8*)&vwb[(o0 + 16) * 512 + ks * 32 + kg * 8];
      acc0 = MFMA16(a, b0, acc0);
      acc1 = MFMA16(a, b1, acc1);
    }
    {
      float vb0 = vb[h * 64 + ntb * 16 + l_lo];
      float vb1 = vb[h * 64 + (ntb + 1) * 16 + l_lo];
#pragma unroll
      for (int r = 0; r < 4; r++){
        int t = mt * 16 + kg * 4 + r;
        long loc = (long)base + lbn + t;
        long b = loc >> 12, n = loc & 4095;
        float* op = out + (((b * 8 + h) * 4096 + n) << 6);
        op[ntb * 16 + l_lo]       = acc0[r] + vb0;
        op[(ntb + 1) * 16 + l_lo] = acc1[r] + vb1;
      }
    }
    // write-late: next head's tile into the other buffer
    if (h < 7){
#pragma unroll
      for (int j = 0; j < 8; j++)
        *(uint4*)(smem + nxt * K3_TILE + (tr * 520 + cblk + j * 8) * 2) = pre[j];
    }
  }
}

extern "C" void kernel_launch(void* const* d_in, const int* in_sizes, int n_in,
                              void* d_out, int out_size, void* d_ws, size_t ws_size,
                              hipStream_t stream){
  const float* q   = (const float*)d_in[0];
  const float* ctx = (const float*)d_in[1];
  const float* kw  = (const float*)d_in[2];
  // d_in[3] = k_b : cancels in softmax, unused
  const float* vw  = (const float*)d_in[4];
  const float* vb  = (const float*)d_in[5];
  const float* lng = (const float*)d_in[6];
  const float* lnb = (const float*)d_in[7];
  float* out = (float*)d_out;

  u16* kwt = (u16*)d_ws;                 // 512 KB (k_w transposed, bf16)
  u16* vwb = kwt + 512 * 512;            // 512 KB (v_w plain, bf16)
  u16* kqw = vwb + 512 * 512;            // CH * 8 KB (kq, then wctx in place)

  size_t avail = ws_size > (size_t)(1 << 20) ? ws_size - (size_t)(1 << 20) : 0;
  long CH = (long)(avail / 8192);
  if (CH > NLOC) CH = NLOC;
  CH &= ~31L;
  if (CH < 32) CH = 32;

  (void)hipFuncSetAttribute((const void*)k1m,
                      hipFuncAttributeMaxDynamicSharedMemorySize, K1_LDS);
  (void)hipFuncSetAttribute((const void*)k3m,
                      hipFuncAttributeMaxDynamicSharedMemorySize, K3_LDS);

  hipLaunchKernelGGL(k0_prep, dim3(1024), dim3(256), 0, stream, kw, vw, kwt, vwb);
  for (long base = 0; base < NLOC; base += CH){
    long M = NLOC - base; if (M > CH) M = CH;
    hipLaunchKernelGGL(k1m, dim3(M / 32), dim3(256), K1_LDS, stream,
                       q, lng, lnb, kwt, kqw, (int)base);
    hipLaunchKernelGGL(k2m, dim3(M), dim3(256), 0, stream, ctx, kqw, (int)base);
    hipLaunchKernelGGL(k3m, dim3(M / 32), dim3(256), K3_LDS, stream,
                       kqw, vwb, vb, out, (int)base);
  }
}

// Round 5
// 278.602 us; speedup vs baseline: 1.9891x; 1.0461x over previous
//
#include <hip/hip_runtime.h>
#include <hip/hip_bf16.h>

typedef unsigned int u32;
typedef unsigned short u16;
typedef __attribute__((ext_vector_type(8))) short short8;
typedef __attribute__((ext_vector_type(4))) float f32x4;

#define NLOC 8192      // B*HWC
#define LCTX 32
#define NH   8

__device__ __forceinline__ float bl(u32 u){ return __uint_as_float(u << 16); }
__device__ __forceinline__ float bh(u32 u){ return __uint_as_float(u & 0xffff0000u); }
__device__ __forceinline__ u16 f2b(float f){
  u32 u = __float_as_uint(f);
  return (u16)((u + 0x7fffu + ((u >> 16) & 1u)) >> 16);
}
__device__ __forceinline__ u32 pk2(float a, float b){
  return (u32)f2b(a) | ((u32)f2b(b) << 16);
}
#define MFMA16(a, b, c) __builtin_amdgcn_mfma_f32_16x16x32_bf16(a, b, c, 0, 0, 0)

// K0: kwt[c][o] = bf16(k_w[o][c]); vwb[o][c] = bf16(v_w[o][c]).
__global__ __launch_bounds__(256) void k0_prep(const float* __restrict__ kw,
                                               const float* __restrict__ vw,
                                               u16* __restrict__ kwt,
                                               u16* __restrict__ vwb){
  int i = blockIdx.x * 256 + threadIdx.x;      // 262144
  int o = i >> 9, c = i & 511;
  kwt[c * 512 + o] = f2b(kw[i]);
  vwb[i] = f2b(vw[i]);
}

// KLN: LayerNorm -> qln bf16 [loc][512]. 1 wave per loc, 4 locs/block.
__global__ __launch_bounds__(256) void kln(const float* __restrict__ q,
                                           const float* __restrict__ lng,
                                           const float* __restrict__ lnb,
                                           u16* __restrict__ qln){
  int tid = threadIdx.x;
  int lane = tid & 63, wv = tid >> 6;
  long bn = (long)blockIdx.x * 4 + wv;
  const float4* qr = (const float4*)(q + bn * 512);
  float4 v0 = qr[lane * 2], v1 = qr[lane * 2 + 1];
  float s  = v0.x + v0.y + v0.z + v0.w + v1.x + v1.y + v1.z + v1.w;
  float s2 = v0.x*v0.x + v0.y*v0.y + v0.z*v0.z + v0.w*v0.w
           + v1.x*v1.x + v1.y*v1.y + v1.z*v1.z + v1.w*v1.w;
#pragma unroll
  for (int d = 1; d < 64; d <<= 1){ s += __shfl_xor(s, d); s2 += __shfl_xor(s2, d); }
  float mu = s * (1.f / 512.f);
  float rstd = rsqrtf(s2 * (1.f / 512.f) - mu * mu + 1e-5f);
  int c = lane * 8;
  float4 g0 = *(const float4*)&lng[c], g1 = *(const float4*)&lng[c + 4];
  float4 b0 = *(const float4*)&lnb[c], b1 = *(const float4*)&lnb[c + 4];
  uint4 st;
  st.x = pk2((v0.x - mu) * rstd * g0.x + b0.x, (v0.y - mu) * rstd * g0.y + b0.y);
  st.y = pk2((v0.z - mu) * rstd * g0.z + b0.z, (v0.w - mu) * rstd * g0.w + b0.w);
  st.z = pk2((v1.x - mu) * rstd * g1.x + b1.x, (v1.y - mu) * rstd * g1.y + b1.y);
  st.w = pk2((v1.z - mu) * rstd * g1.z + b1.z, (v1.w - mu) * rstd * g1.w + b1.w);
  *(uint4*)&qln[bn * 512 + c] = st;
}

// K1g: kq[t,h,c] = sum_d qln[t,h*64+d]*kwt[c,h*64+d] via MFMA.
// Grid (locs/64, 8 heads), 256 thr. A = qln slice [64t][64d] (LDS swizzled);
// Bt = kwt [c][o] from L2. Out staged in ktmp then coalesced to kqw.
#define K1G_LDS (8192 + 64 * 520 * 2)
__global__ __launch_bounds__(256) void k1g(const u16* __restrict__ qln,
                                           const u16* __restrict__ kwt,
                                           u16* __restrict__ kqw,
                                           int base){
  extern __shared__ char smem[];
  char* qs = smem;                          // [64 rows][128 B] swizzled
  u16* ktmp = (u16*)(smem + 8192);          // [64][520]
  int tid = threadIdx.x;
  int lane = tid & 63, w = tid >> 6;
  int h = blockIdx.y;
  long t0 = (long)blockIdx.x * 64;          // chunk-local loc base
  long g0 = (long)base + t0;                // global loc base
  // stage qln head-slice
  {
    int t = tid >> 2, part = tid & 3;
    const char* src = (const char*)(qln + (g0 + t) * 512 + h * 64) + part * 32;
    uint4 a = *(const uint4*)src;
    uint4 b = *(const uint4*)(src + 16);
    int sw = (t & 7) << 4, off = part * 32;
    *(uint4*)(qs + t * 128 + (off ^ sw)) = a;
    *(uint4*)(qs + t * 128 + ((off + 16) ^ sw)) = b;
  }
  __syncthreads();
  int l_lo = lane & 15, kg = lane >> 4;
  short8 afr[4][2];
#pragma unroll
  for (int mt = 0; mt < 4; mt++)
#pragma unroll
    for (int ks = 0; ks < 2; ks++){
      int trow = mt * 16 + l_lo;
      afr[mt][ks] = *(const short8*)(qs + trow * 128 +
                    ((ks * 64 + kg * 16) ^ ((trow & 7) << 4)));
    }
#pragma unroll
  for (int nt = 0; nt < 8; nt++){
    int c = w * 128 + nt * 16 + l_lo;
    short8 bfr0 = *(const short8*)&kwt[c * 512 + h * 64 + kg * 8];
    short8 bfr1 = *(const short8*)&kwt[c * 512 + h * 64 + 32 + kg * 8];
    f32x4 acc[4];
#pragma unroll
    for (int mt = 0; mt < 4; mt++){
      acc[mt] = (f32x4){0.f, 0.f, 0.f, 0.f};
      acc[mt] = MFMA16(afr[mt][0], bfr0, acc[mt]);
      acc[mt] = MFMA16(afr[mt][1], bfr1, acc[mt]);
    }
#pragma unroll
    for (int mt = 0; mt < 4; mt++)
#pragma unroll
      for (int r = 0; r < 4; r++)
        ktmp[(mt * 16 + kg * 4 + r) * 520 + c] = f2b(acc[mt][r]);
  }
  __syncthreads();
  // coalesced copy to kqw
  {
    int tr = tid >> 2, seg = tid & 3;
    u16* dst = &kqw[((t0 + tr) * 8 + h) * 512];
#pragma unroll
    for (int j = 0; j < 16; j++)
      *(uint4*)&dst[seg * 128 + j * 8] = *(const uint4*)&ktmp[tr * 520 + seg * 128 + j * 8];
  }
}

// K2m: per-location attention core (unchanged from round 4).
__global__ __launch_bounds__(256) void k2m(const float* __restrict__ ctx,
                                           u16* __restrict__ kqw,  // in: kq, out: wctx
                                           int base){
  __shared__ char ctxs[32 * 1024];          // bf16 [32 l][1024 B], XOR-swizzled
  __shared__ char kqs[8 * 1024];            // bf16 [8 h][1024 B], XOR-swizzled
  __shared__ float smat4[4 * 32 * 8];       // per-wave score partials [w][l][h]
  __shared__ float ssum[32 * 8];            // summed scores [l][h]
  __shared__ __align__(16) float wls[32 * 8]; // softmax weights [l][h]
  int tid = threadIdx.x;
  int lane = tid & 63, w = tid >> 6;
  long bn = (long)base + blockIdx.x;
  const float4* cp = (const float4*)(ctx + bn * (32 * 512));
#pragma unroll
  for (int i = 0; i < 16; i++){
    float4 v = cp[i * 256 + tid];
    int e0 = (i * 256 + tid) * 4;
    int l = e0 >> 9, col = e0 & 511;
    uint2 pk; pk.x = pk2(v.x, v.y); pk.y = pk2(v.z, v.w);
    *(uint2*)(ctxs + l * 1024 + ((col * 2) ^ ((l & 7) << 4))) = pk;
  }
  const u32* kqp = (const u32*)(kqw + (long)blockIdx.x * 4096);
#pragma unroll
  for (int r = 0; r < 8; r++){
    int m = r * 256 + tid;
    u32 u = kqp[m];
    int e0 = m * 2;
    int h = e0 >> 9, c = e0 & 511;
    *(u32*)(kqs + h * 1024 + ((c * 2) ^ (h << 4))) = u;
  }
  __syncthreads();
  {
    int l_lo = lane & 15, kg = lane >> 4, hb = lane & 7;
    f32x4 acc0 = {0.f,0.f,0.f,0.f}, acc1 = {0.f,0.f,0.f,0.f};
#pragma unroll
    for (int s = 0; s < 4; s++){
      int coff = (w * 4 + s) * 64 + kg * 16;
      short8 bfr = *(const short8*)(kqs + hb * 1024 + (coff ^ (hb << 4)));
      short8 a0 = *(const short8*)(ctxs + l_lo * 1024 + (coff ^ ((l_lo & 7) << 4)));
      int l1 = l_lo + 16;
      short8 a1 = *(const short8*)(ctxs + l1 * 1024 + (coff ^ ((l1 & 7) << 4)));
      acc0 = MFMA16(a0, bfr, acc0);
      acc1 = MFMA16(a1, bfr, acc1);
    }
    if (l_lo < 8){
#pragma unroll
      for (int r = 0; r < 4; r++){
        smat4[(w * 32 + kg * 4 + r) * 8 + l_lo]      = acc0[r];
        smat4[(w * 32 + 16 + kg * 4 + r) * 8 + l_lo] = acc1[r];
      }
    }
  }
  __syncthreads();
  {
    int l = tid >> 3, h = tid & 7;
    int ix = l * 8 + h;
    ssum[ix] = smat4[ix] + smat4[256 + ix] + smat4[512 + ix] + smat4[768 + ix];
  }
  __syncthreads();
  {
    int l = tid >> 3, h = tid & 7;
    float sv = ssum[l * 8 + h];
    float mx = ssum[h];
#pragma unroll
    for (int j = 1; j < 32; j++) mx = fmaxf(mx, ssum[j * 8 + h]);
    float S = 0.f;
#pragma unroll
    for (int j = 0; j < 32; j++) S += __expf(ssum[j * 8 + h] - mx);
    wls[l * 8 + h] = __expf(sv - mx) / S;
  }
  __syncthreads();
  float acc[16];
#pragma unroll
  for (int i = 0; i < 16; i++) acc[i] = 0.f;
#pragma unroll 4
  for (int l2 = 0; l2 < 32; l2++){
    u32 cv = *(const u32*)(ctxs + l2 * 1024 + ((4 * tid) ^ ((l2 & 7) << 4)));
    float x = bl(cv), y = bh(cv);
    float4 w0 = *(const float4*)&wls[l2 * 8];
    float4 w1 = *(const float4*)&wls[l2 * 8 + 4];
    acc[0] += w0.x * x; acc[1] += w0.x * y;
    acc[2] += w0.y * x; acc[3] += w0.y * y;
    acc[4] += w0.z * x; acc[5] += w0.z * y;
    acc[6] += w0.w * x; acc[7] += w0.w * y;
    acc[8] += w1.x * x; acc[9] += w1.x * y;
    acc[10]+= w1.y * x; acc[11]+= w1.y * y;
    acc[12]+= w1.z * x; acc[13]+= w1.z * y;
    acc[14]+= w1.w * x; acc[15]+= w1.w * y;
  }
  u32* wp = (u32*)(kqw + (long)blockIdx.x * 4096);
#pragma unroll
  for (int hh = 0; hh < 8; hh++)
    wp[hh * 256 + tid] = pk2(acc[hh * 2], acc[hh * 2 + 1]);
}

// K3g: out[t,h,d] = sum_c wctx[t,h,c]*vwb[h*64+d,c] + vb. Grid (locs/64, 8).
// A = wctx head-slice [64t][512c] (LDS swizzled, 64KB); Bt = vwb from L2.
#define K3G_LDS (64 * 1024)
__global__ __launch_bounds__(256) void k3g(const u16* __restrict__ wctx,
                                           const u16* __restrict__ vwb,
                                           const float* __restrict__ vb,
                                           float* __restrict__ out,
                                           int base){
  extern __shared__ char smem[];            // [64 rows][1024 B] swizzled
  int tid = threadIdx.x;
  int lane = tid & 63, w = tid >> 6;
  int h = blockIdx.y;
  long t0 = (long)blockIdx.x * 64;
  {
    int tr = tid >> 2, seg = tid & 3;
    const char* src = (const char*)&wctx[((t0 + tr) * 8 + h) * 512];
    int sw = (tr & 7) << 4;
#pragma unroll
    for (int j = 0; j < 16; j++){
      int off = seg * 256 + j * 16;
      *(uint4*)(smem + tr * 1024 + (off ^ sw)) = *(const uint4*)(src + off);
    }
  }
  __syncthreads();
  int l_lo = lane & 15, kg = lane >> 4;
  int trow = w * 16 + l_lo;
  const char* arow = smem + trow * 1024;
  int sw = (trow & 7) << 4;
  f32x4 acc[4];
#pragma unroll
  for (int nt = 0; nt < 4; nt++) acc[nt] = (f32x4){0.f, 0.f, 0.f, 0.f};
#pragma unroll 4
  for (int ks = 0; ks < 16; ks++){
    short8 a = *(const short8*)(arow + ((ks * 64 + kg * 16) ^ sw));
#pragma unroll
    for (int nt = 0; nt < 4; nt++){
      int o = h * 64 + nt * 16 + l_lo;
      short8 b = *(const short8*)&vwb[o * 512 + ks * 32 + kg * 8];
      acc[nt] = MFMA16(a, b, acc[nt]);
    }
  }
#pragma unroll
  for (int nt = 0; nt < 4; nt++){
    float vbn = vb[h * 64 + nt * 16 + l_lo];
#pragma unroll
    for (int r = 0; r < 4; r++){
      int t = w * 16 + kg * 4 + r;
      long loc = (long)base + t0 + t;
      long b = loc >> 12, n = loc & 4095;
      out[(((b * 8 + h) * 4096 + n) << 6) + nt * 16 + l_lo] = acc[nt][r] + vbn;
    }
  }
}

extern "C" void kernel_launch(void* const* d_in, const int* in_sizes, int n_in,
                              void* d_out, int out_size, void* d_ws, size_t ws_size,
                              hipStream_t stream){
  const float* q   = (const float*)d_in[0];
  const float* ctx = (const float*)d_in[1];
  const float* kw  = (const float*)d_in[2];
  // d_in[3] = k_b : cancels in softmax, unused
  const float* vw  = (const float*)d_in[4];
  const float* vb  = (const float*)d_in[5];
  const float* lng = (const float*)d_in[6];
  const float* lnb = (const float*)d_in[7];
  float* out = (float*)d_out;

  u16* kwt = (u16*)d_ws;                 // 512 KB
  u16* vwb = kwt + 512 * 512;            // 512 KB
  u16* qln = vwb + 512 * 512;            // 8 MB (LN'd q, bf16)
  u16* kqw = qln + (long)NLOC * 512;     // CH * 8 KB (kq, then wctx in place)

  size_t resv = 2u * 512 * 1024 + (size_t)NLOC * 1024;
  size_t avail = ws_size > resv ? ws_size - resv : 0;
  long CH = (long)(avail / 8192);
  if (CH > NLOC) CH = NLOC;
  CH &= ~63L;
  if (CH < 64) CH = 64;

  (void)hipFuncSetAttribute((const void*)k1g,
                      hipFuncAttributeMaxDynamicSharedMemorySize, K1G_LDS);
  (void)hipFuncSetAttribute((const void*)k3g,
                      hipFuncAttributeMaxDynamicSharedMemorySize, K3G_LDS);

  hipLaunchKernelGGL(k0_prep, dim3(1024), dim3(256), 0, stream, kw, vw, kwt, vwb);
  hipLaunchKernelGGL(kln, dim3(NLOC / 4), dim3(256), 0, stream, q, lng, lnb, qln);
  for (long base = 0; base < NLOC; base += CH){
    long M = NLOC - base; if (M > CH) M = CH;
    hipLaunchKernelGGL(k1g, dim3(M / 64, 8), dim3(256), K1G_LDS, stream,
                       qln, kwt, kqw, (int)base);
    hipLaunchKernelGGL(k2m, dim3(M), dim3(256), 0, stream, ctx, kqw, (int)base);
    hipLaunchKernelGGL(k3g, dim3(M / 64, 8), dim3(256), K3G_LDS, stream,
                       kqw, vwb, vb, out, (int)base);
  }
}